// Round 4
// baseline (3009.547 us; speedup 1.0000x reference)
//
#include <hip/hip_runtime.h>
#include <hip/hip_bf16.h>

// Problem constants
#define BB   2
#define NN   50000
#define BN   100000     // B*N
#define IND  64
#define HIDD 256
#define OUTD 128
#define NE   500000

using u16 = unsigned short;
using u32 = unsigned int;
using s64 = long long;

// ---------------------------------------------------------------------------
// Kernel 1: h = relu(x @ nw1 + nb1) @ nw2 + nb2   -> hbuf (f32, [BN][128])
// 32 rows/block, 256 threads.
// ---------------------------------------------------------------------------
__global__ __launch_bounds__(256) void node_mlp_kernel(
    const float* __restrict__ x, const float* __restrict__ nw1, const float* __restrict__ nb1,
    const float* __restrict__ nw2, const float* __restrict__ nb2, float* __restrict__ hbuf)
{
    __shared__ float xs[32 * 64];     // 8 KB
    __shared__ float hid[32 * 256];   // 32 KB
    const int t  = threadIdx.x;
    const int r0 = blockIdx.x * 32;

    // stage x tile: 32 rows x 64 f32 = 512 float4, 2 per thread
    #pragma unroll
    for (int it = 0; it < 2; ++it) {
        int i = t + it * 256;
        int m = i >> 4, c = i & 15;       // row, float4-col
        ((float4*)xs)[m * 16 + c] = ((const float4*)x)[(r0 + m) * 16 + c];
    }
    __syncthreads();

    // phase B: hid = relu(xs @ nw1 + nb1), K=64
    {
        float acc[32];
        #pragma unroll
        for (int m = 0; m < 32; ++m) acc[m] = 0.f;
        for (int k4 = 0; k4 < 16; ++k4) {
            float w0 = nw1[(k4*4+0)*256 + t];
            float w1 = nw1[(k4*4+1)*256 + t];
            float w2 = nw1[(k4*4+2)*256 + t];
            float w3 = nw1[(k4*4+3)*256 + t];
            #pragma unroll
            for (int m = 0; m < 32; ++m) {
                float4 e = ((const float4*)xs)[m*16 + k4];  // broadcast
                acc[m] = fmaf(e.x, w0, acc[m]);
                acc[m] = fmaf(e.y, w1, acc[m]);
                acc[m] = fmaf(e.z, w2, acc[m]);
                acc[m] = fmaf(e.w, w3, acc[m]);
            }
        }
        float b1 = nb1[t];
        #pragma unroll
        for (int m = 0; m < 32; ++m) hid[m*256 + t] = fmaxf(acc[m] + b1, 0.f);
    }
    __syncthreads();

    // phase C: out = hid @ nw2 + nb2, K=256
    {
        const int o = t & 127, mh = t >> 7;  // mh wave-uniform
        float acc[16];
        #pragma unroll
        for (int i = 0; i < 16; ++i) acc[i] = 0.f;
        for (int k4 = 0; k4 < 64; ++k4) {
            float w0 = nw2[(k4*4+0)*128 + o];
            float w1 = nw2[(k4*4+1)*128 + o];
            float w2 = nw2[(k4*4+2)*128 + o];
            float w3 = nw2[(k4*4+3)*128 + o];
            #pragma unroll
            for (int mm = 0; mm < 16; ++mm) {
                float4 h4 = ((const float4*)hid)[(mh*16+mm)*64 + k4];  // broadcast
                acc[mm] = fmaf(h4.x, w0, acc[mm]);
                acc[mm] = fmaf(h4.y, w1, acc[mm]);
                acc[mm] = fmaf(h4.z, w2, acc[mm]);
                acc[mm] = fmaf(h4.w, w3, acc[mm]);
            }
        }
        float b2 = nb2[o];
        #pragma unroll
        for (int mm = 0; mm < 16; ++mm)
            hbuf[(r0 + mh*16 + mm) * 128 + o] = acc[mm] + b2;
    }
}

// ---------------------------------------------------------------------------
// Kernel 2: edge MLP + scatter. Robust to edges arriving as int32 OR int64:
// probe odd 32-bit words 1..63 — all-zero <=> int64 (high halves of idx<50000).
// (Measured: behavior identical to plain-int32 rounds => edges are int32; the
//  probe is kept because it is provably-safe and costless.)
// ---------------------------------------------------------------------------
__global__ __launch_bounds__(256) void edge_mlp_kernel(
    const float* __restrict__ x, const int* __restrict__ edges,
    const float* __restrict__ ew1, const float* __restrict__ eb1,
    const float* __restrict__ ew2, const float* __restrict__ eb2,
    float* __restrict__ hbuf)
{
    __shared__ float ein[32 * 128];   // 16 KB
    __shared__ float hid[32 * 256];   // 32 KB
    __shared__ int us[32], vs[32];
    __shared__ int is64;
    const int t  = threadIdx.x;
    const int b  = blockIdx.y;
    const int e0 = blockIdx.x * 32;

    if (t == 0) {
        int nz = 0;
        #pragma unroll
        for (int k = 1; k < 64; k += 2) nz |= edges[k];
        is64 = (nz == 0) ? 1 : 0;
    }
    __syncthreads();

    if (t < 32) {
        if (is64) {
            us[t] = (int)((const s64*)edges)[(e0 + t) * 2 + 0];
            vs[t] = (int)((const s64*)edges)[(e0 + t) * 2 + 1];
        } else {
            us[t] = edges[(e0 + t) * 2 + 0];
            vs[t] = edges[(e0 + t) * 2 + 1];
        }
    }
    __syncthreads();

    // gather: row = 32 float4 (16 from x[u], 16 from x[v]); 1024 total, 4/thread
    #pragma unroll
    for (int it = 0; it < 4; ++it) {
        int i = t + it * 256;
        int m = i >> 5, c = i & 31;
        int node = (c < 16) ? us[m] : vs[m];
        ((float4*)ein)[m * 32 + c] =
            ((const float4*)x)[(b * NN + node) * 16 + (c & 15)];
    }
    __syncthreads();

    // phase B: hid = relu(ein @ ew1 + eb1), K=128
    {
        float acc[32];
        #pragma unroll
        for (int m = 0; m < 32; ++m) acc[m] = 0.f;
        for (int k4 = 0; k4 < 32; ++k4) {
            float w0 = ew1[(k4*4+0)*256 + t];
            float w1 = ew1[(k4*4+1)*256 + t];
            float w2 = ew1[(k4*4+2)*256 + t];
            float w3 = ew1[(k4*4+3)*256 + t];
            #pragma unroll
            for (int m = 0; m < 32; ++m) {
                float4 e = ((const float4*)ein)[m*32 + k4];  // broadcast
                acc[m] = fmaf(e.x, w0, acc[m]);
                acc[m] = fmaf(e.y, w1, acc[m]);
                acc[m] = fmaf(e.z, w2, acc[m]);
                acc[m] = fmaf(e.w, w3, acc[m]);
            }
        }
        float b1 = eb1[t];
        #pragma unroll
        for (int m = 0; m < 32; ++m) hid[m*256 + t] = fmaxf(acc[m] + b1, 0.f);
    }
    __syncthreads();

    // phase C: emb = hid @ ew2 + eb2, K=256, then scatter-add
    {
        const int o = t & 127, mh = t >> 7;
        float acc[16];
        #pragma unroll
        for (int i = 0; i < 16; ++i) acc[i] = 0.f;
        for (int k4 = 0; k4 < 64; ++k4) {
            float w0 = ew2[(k4*4+0)*128 + o];
            float w1 = ew2[(k4*4+1)*128 + o];
            float w2 = ew2[(k4*4+2)*128 + o];
            float w3 = ew2[(k4*4+3)*128 + o];
            #pragma unroll
            for (int mm = 0; mm < 16; ++mm) {
                float4 h4 = ((const float4*)hid)[(mh*16+mm)*64 + k4];  // broadcast
                acc[mm] = fmaf(h4.x, w0, acc[mm]);
                acc[mm] = fmaf(h4.y, w1, acc[mm]);
                acc[mm] = fmaf(h4.z, w2, acc[mm]);
                acc[mm] = fmaf(h4.w, w3, acc[mm]);
            }
        }
        float b2 = eb2[o];
        #pragma unroll
        for (int mm = 0; mm < 16; ++mm) {
            int m = mh*16 + mm;
            float val = acc[mm] + b2;
            atomicAdd(&hbuf[(b * NN + us[m]) * 128 + o], val);
            atomicAdd(&hbuf[(b * NN + vs[m]) * 128 + o], val);
        }
    }
}

// ---------------------------------------------------------------------------
// Kernel 3: recon = hbuf @ dw + db -> f32 out. 64 rows/block.
// ---------------------------------------------------------------------------
__global__ __launch_bounds__(256) void decode_kernel(
    const float* __restrict__ hbuf, const float* __restrict__ dw, const float* __restrict__ db,
    float* __restrict__ out)
{
    __shared__ float hs[64 * 128];    // 32 KB
    const int t  = threadIdx.x;
    const int r0 = blockIdx.x * 64;

    #pragma unroll
    for (int it = 0; it < 8; ++it) {
        int i = t + it * 256;         // 0..2047
        int m = i >> 5, c = i & 31;
        int r = r0 + m;
        float4 v = (r < BN) ? ((const float4*)hbuf)[r * 32 + c]
                            : make_float4(0.f, 0.f, 0.f, 0.f);
        ((float4*)hs)[m * 32 + c] = v;
    }
    __syncthreads();

    const int d = t & 63, g = t >> 6;   // g wave-uniform
    float acc[16];
    #pragma unroll
    for (int i = 0; i < 16; ++i) acc[i] = 0.f;
    for (int k4 = 0; k4 < 32; ++k4) {
        float w0 = dw[(k4*4+0)*64 + d];
        float w1 = dw[(k4*4+1)*64 + d];
        float w2 = dw[(k4*4+2)*64 + d];
        float w3 = dw[(k4*4+3)*64 + d];
        #pragma unroll
        for (int mm = 0; mm < 16; ++mm) {
            float4 h4 = ((const float4*)hs)[(g*16+mm)*32 + k4];  // broadcast
            acc[mm] = fmaf(h4.x, w0, acc[mm]);
            acc[mm] = fmaf(h4.y, w1, acc[mm]);
            acc[mm] = fmaf(h4.z, w2, acc[mm]);
            acc[mm] = fmaf(h4.w, w3, acc[mm]);
        }
    }
    float bd = db[d];
    #pragma unroll
    for (int mm = 0; mm < 16; ++mm) {
        int r = r0 + g*16 + mm;
        if (r < BN) out[r * 64 + d] = acc[mm] + bd;
    }
}

// ---------------------------------------------------------------------------
extern "C" void kernel_launch(void* const* d_in, const int* in_sizes, int n_in,
                              void* d_out, int out_size, void* d_ws, size_t ws_size,
                              hipStream_t stream) {
    const float* x     = (const float*)d_in[0];
    const int*   edges = (const int*)d_in[1];
    const float* ew1   = (const float*)d_in[2];
    const float* eb1   = (const float*)d_in[3];
    const float* ew2   = (const float*)d_in[4];
    const float* eb2   = (const float*)d_in[5];
    const float* nw1   = (const float*)d_in[6];
    const float* nb1   = (const float*)d_in[7];
    const float* nw2   = (const float*)d_in[8];
    const float* nb2   = (const float*)d_in[9];
    const float* dw    = (const float*)d_in[10];
    const float* db    = (const float*)d_in[11];
    float* hbuf = (float*)d_ws;   // BN*128 f32 = 51.2 MB

    node_mlp_kernel<<<BN / 32, 256, 0, stream>>>(x, nw1, nb1, nw2, nb2, hbuf);
    edge_mlp_kernel<<<dim3(NE / 32, BB), 256, 0, stream>>>(x, edges, ew1, eb1, ew2, eb2, hbuf);
    decode_kernel<<<(BN + 63) / 64, 256, 0, stream>>>(hbuf, dw, db, (float*)d_out);
}